// Round 14
// baseline (355.913 us; speedup 1.0000x reference)
//
#include <hip/hip_runtime.h>
#include <hip/hip_bf16.h>

// GraphSAGE 2-layer: radix-bucket CSR build + bf16 MFMA transform-then-aggregate.
// N=100000, E=3.2M, IN=256, H=128, OUT=64.
// CSR: fine hist (dst>>7) -> scan -> coarse scatter (dst>>12) -> fine scatter -> bucket sort.
// Layer-1 GEMM: fragment-ordered B in LDS (conflict-free), 8 waves, reg double-buffer.
// agg1 FUSED with layer-2 GEMM: gather->h rows in LDS -> MFMA vs Wt2 -> t2s/t2n.
// Neighbor buffers fp8-e4m3.

typedef unsigned int uint32;
typedef __attribute__((ext_vector_type(8))) short short8;
typedef __attribute__((ext_vector_type(4))) float f32x4;
typedef __attribute__((ext_vector_type(2))) float f32x2;

#define NBMAX 1024     // max fine buckets (N <= 131072 at 128 nodes/bucket)
#define NQMAX 32       // max coarse buckets (4096 nodes each)
#define EPB   4096     // edges per block in hist/scatter passes

#if defined(__has_builtin)
#if __has_builtin(__builtin_amdgcn_cvt_pk_f32_fp8) && __has_builtin(__builtin_amdgcn_cvt_pk_fp8_f32)
#define FP8_HW 1
#endif
#endif
#ifndef FP8_HW
#define FP8_HW 0
#endif

__device__ __forceinline__ unsigned short f2bf(float f) {
    unsigned u = __float_as_uint(f);
    u += 0x7fffu + ((u >> 16) & 1u);      // RNE
    return (unsigned short)(u >> 16);
}
__device__ __forceinline__ uint32 pack2bf(float lo, float hi) {
    return (uint32)f2bf(lo) | ((uint32)f2bf(hi) << 16);
}
__device__ __forceinline__ float bf_lo(uint32 v) { return __uint_as_float(v << 16); }
__device__ __forceinline__ float bf_hi(uint32 v) { return __uint_as_float(v & 0xFFFF0000u); }

// ---- fp8 e4m3 encode/decode ----
__device__ __forceinline__ unsigned char enc8(float v) {
#if FP8_HW
    return (unsigned char)(__builtin_amdgcn_cvt_pk_fp8_f32(v, v, 0, false) & 0xFF);
#else
    float g = v * 0x1p-120f;
    uint32 b = __float_as_uint(g);
    uint32 s = (b >> 24) & 0x80u;
    b &= 0x7fffffffu;
    b += 0x7ffffu + ((b >> 20) & 1u);     // RNE to 3 mantissa bits
    int t = (int)(b >> 20) - 960;
    t = t < 0 ? 0 : (t > 126 ? 126 : t);
    return (unsigned char)(s | (uint32)t);
#endif
}
#if !FP8_HW
__device__ __forceinline__ float dec1(uint32 b) {
    uint32 bits = ((b & 0x80u) << 24) | ((b & 0x7fu) << 20);
    return __uint_as_float(bits) * 0x1p+120f;
}
#endif

// decode 2 fp8 (word lo/hi of u, compile-time selector) -> packed float pair
template<bool HI>
__device__ __forceinline__ f32x2 cvt2(uint32 u) {
#if FP8_HW
    auto t = __builtin_amdgcn_cvt_pk_f32_fp8(u, HI);
    f32x2 r; r[0] = t[0]; r[1] = t[1];
    return r;
#else
    uint32 a = HI ? (u >> 16) : u;
    f32x2 r; r[0] = dec1(a & 0xffu); r[1] = dec1((a >> 8) & 0xffu);
    return r;
#endif
}

// accumulate 8 fp8 values (uint2) into 4 packed-pair accumulators
__device__ __forceinline__ void acc8(f32x2* acc, uint2 v) {
    acc[0] += cvt2<false>(v.x); acc[1] += cvt2<true>(v.x);
    acc[2] += cvt2<false>(v.y); acc[3] += cvt2<true>(v.y);
}

__device__ __forceinline__ f32x2 shfl_xor2(f32x2 v, int m) {
    union { f32x2 f; long long l; } u;
    u.f = v;
    u.l = __shfl_xor(u.l, m);
    return u.f;
}

// ---------------- pass A: fine histogram (bucket = dst >> 7) ----------------
__global__ __launch_bounds__(256) void k_hist_fine(const int* __restrict__ dst, int E,
                                                   int* __restrict__ bcnt) {
    __shared__ int hist[NBMAX];
    for (int i = threadIdx.x; i < NBMAX; i += 256) hist[i] = 0;
    __syncthreads();
    int base = blockIdx.x * EPB;
    #pragma unroll 4
    for (int i = 0; i < EPB / 256; ++i) {
        int e = base + i * 256 + threadIdx.x;
        if (e < E) atomicAdd(&hist[dst[e] >> 7], 1);
    }
    __syncthreads();
    for (int i = threadIdx.x; i < NBMAX; i += 256) {
        int h = hist[i];
        if (h) atomicAdd(&bcnt[i], h);
    }
}

// ---------------- scan: fine offsets + fills, coarse fills ----------------
__global__ __launch_bounds__(1024) void k_scan(const int* __restrict__ bcnt, int NBF, int NQ,
                                               int* __restrict__ boffs, int* __restrict__ gfill_fine,
                                               int* __restrict__ gfillq, int E) {
    __shared__ int sd[1024];
    int tid = threadIdx.x;
    int v = (tid < NBF) ? bcnt[tid] : 0;
    sd[tid] = v;
    __syncthreads();
    for (int off = 1; off < 1024; off <<= 1) {
        int t = (tid >= off) ? sd[tid - off] : 0;
        __syncthreads();
        sd[tid] += t;
        __syncthreads();
    }
    int excl = sd[tid] - v;
    if (tid < NBF) { boffs[tid] = excl; gfill_fine[tid] = excl; }
    if (tid == 0) boffs[NBF] = E;
    __syncthreads();
    if (tid < NQ) {
        int f = tid * 32;
        gfillq[tid] = (f < NBF) ? (sd[f] - ((f < NBF) ? bcnt[f] : 0)) : E;
    }
}

// ---------------- pass B: coarse scatter (q = dst >> 12) ----------------
__global__ __launch_bounds__(256) void k_scatter_coarse(const int* __restrict__ src,
                                                        const int* __restrict__ dst, int E,
                                                        int* __restrict__ gfillq,
                                                        uint32* __restrict__ pairs1) {
    __shared__ int hist[NQMAX];
    __shared__ int basea[NQMAX];
    if (threadIdx.x < NQMAX) hist[threadIdx.x] = 0;
    __syncthreads();
    int base = blockIdx.x * EPB;
    #pragma unroll 4
    for (int i = 0; i < EPB / 256; ++i) {
        int e = base + i * 256 + threadIdx.x;
        if (e < E) atomicAdd(&hist[dst[e] >> 12], 1);
    }
    __syncthreads();
    if (threadIdx.x < NQMAX) {
        int h = hist[threadIdx.x];
        basea[threadIdx.x] = h ? atomicAdd(&gfillq[threadIdx.x], h) : 0;
        hist[threadIdx.x] = 0;
    }
    __syncthreads();
    #pragma unroll 4
    for (int i = 0; i < EPB / 256; ++i) {
        int e = base + i * 256 + threadIdx.x;
        if (e < E) {
            int d = dst[e];
            int q = d >> 12;
            int pos = basea[q] + atomicAdd(&hist[q], 1);
            pairs1[pos] = ((uint32)src[e] << 12) | (uint32)(d & 4095);
        }
    }
}

// ---------------- pass C: fine scatter within coarse segments ----------------
__global__ __launch_bounds__(256) void k_scatter_fine(const uint32* __restrict__ pairs1,
                                                      const int* __restrict__ boffs,
                                                      const int* __restrict__ qend,
                                                      int* __restrict__ gfill_fine,
                                                      uint32* __restrict__ pairs2, int NC) {
    __shared__ int hist[32];
    __shared__ int basea[32];
    const int q = blockIdx.x;
    const int s0 = boffs[q * 32];
    const int s1 = qend[q];
    for (long cb = (long)s0 + (long)blockIdx.y * EPB; cb < s1; cb += (long)NC * EPB) {
        int cend = (int)((cb + EPB < s1) ? cb + EPB : s1);
        if (threadIdx.x < 32) hist[threadIdx.x] = 0;
        __syncthreads();
        for (int e = (int)cb + threadIdx.x; e < cend; e += 256)
            atomicAdd(&hist[(pairs1[e] >> 7) & 31], 1);
        __syncthreads();
        if (threadIdx.x < 32) {
            int h = hist[threadIdx.x];
            basea[threadIdx.x] = h ? atomicAdd(&gfill_fine[q * 32 + threadIdx.x], h) : 0;
            hist[threadIdx.x] = 0;
        }
        __syncthreads();
        for (int e = (int)cb + threadIdx.x; e < cend; e += 256) {
            uint32 p = pairs1[e];
            int fl = (p >> 7) & 31;
            int pos = basea[fl] + atomicAdd(&hist[fl], 1);
            pairs2[pos] = p;
        }
        __syncthreads();
    }
}

// ---------------- pass D: per-fine-bucket sort -> CSR ----------------
__global__ __launch_bounds__(256) void k_bucket_sort(const uint32* __restrict__ pairs,
                                                     const int* __restrict__ boffs,
                                                     int N, int E,
                                                     int* __restrict__ row_start,
                                                     float* __restrict__ deg_inv,
                                                     int* __restrict__ src_sorted) {
    __shared__ int cnt[128];
    __shared__ int sc[128];
    __shared__ int fill[128];
    int b = blockIdx.x, tid = threadIdx.x;
    int s0 = boffs[b], s1 = boffs[b + 1];
    if (tid < 128) cnt[tid] = 0;
    __syncthreads();
    for (int e = s0 + tid; e < s1; e += 256)
        atomicAdd(&cnt[pairs[e] & 127], 1);
    __syncthreads();
    if (tid < 128) sc[tid] = cnt[tid];
    __syncthreads();
    for (int off = 1; off < 128; off <<= 1) {
        int v = 0;
        if (tid < 128 && tid >= off) v = sc[tid - off];
        __syncthreads();
        if (tid < 128) sc[tid] += v;
        __syncthreads();
    }
    if (tid < 128) {
        int excl = sc[tid] - cnt[tid];
        int node = b * 128 + tid;
        if (node < N) {
            row_start[node] = s0 + excl;
            int d = cnt[tid];
            deg_inv[node] = 1.0f / (float)(d > 1 ? d : 1);
        }
        fill[tid] = s0 + excl;
    }
    if (b == 0 && tid == 0) row_start[N] = E;
    __syncthreads();
    for (int e = s0 + tid; e < s1; e += 256) {
        uint32 p = pairs[e];
        int pos = atomicAdd(&fill[p & 127], 1);
        src_sorted[pos] = (int)(p >> 12);
    }
}

// ---------------- x f32 -> bf16 pre-cast (zero-fills pad rows) ----------------
__global__ __launch_bounds__(256) void k_cast_x(const float* __restrict__ x, uint32* __restrict__ xb,
                                                long n8, long total8) {
    long t = (long)blockIdx.x * blockDim.x + threadIdx.x;
    if (t >= total8) return;
    uint4 o = make_uint4(0u, 0u, 0u, 0u);
    if (t < n8) {
        const float4* p = reinterpret_cast<const float4*>(x) + t * 2;
        float4 a = p[0], b = p[1];
        o.x = pack2bf(a.x, a.y); o.y = pack2bf(a.z, a.w);
        o.z = pack2bf(b.x, b.y); o.w = pack2bf(b.z, b.w);
    }
    reinterpret_cast<uint4*>(xb)[t] = o;
}

// transpose+cast weights: Wt[c][k] = (c<halfC ? Ws[k][c] : Wn[k][c-halfC]), row-major [2*halfC][K]
__global__ __launch_bounds__(256) void k_wt(const float* __restrict__ Ws, const float* __restrict__ Wn,
                                            int K, int logK, int halfC, unsigned short* __restrict__ Wt) {
    int t = blockIdx.x * blockDim.x + threadIdx.x;
    int total = 2 * halfC * K;
    if (t >= total) return;
    int c = t >> logK, k = t & (K - 1);
    float v = (c < halfC) ? Ws[(size_t)k * halfC + c] : Wn[(size_t)k * halfC + (c - halfC)];
    Wt[t] = f2bf(v);
}

// ---------------- register-streaming MFMA GEMM (layer 1), fragment-ordered B ----------------
template<int K, int NF, bool YSPLIT>
__global__ __launch_bounds__(512) void gemm_rs(const unsigned short* __restrict__ A, int nstrip,
                                               const unsigned short* __restrict__ Wt,
                                               unsigned short* __restrict__ S16,
                                               unsigned char* __restrict__ N8) {
    constexpr int KS = K / 32;
    __shared__ unsigned short Bs[NF * KS * 512];
    const int tid = threadIdx.x;
    const int wave = tid >> 6, lane = tid & 63;
    const int l15 = lane & 15, l4 = lane >> 4;

    const unsigned short* Wtblk = Wt + (YSPLIT ? (size_t)blockIdx.y * 128 * K : 0);
    const bool out8 = YSPLIT && (blockIdx.y == 1);

    for (int i = tid; i < NF * KS * 64; i += 512) {
        int f = i >> 6, l = i & 63;
        int s = f / NF, n = f - s * NF;
        int col = n * 16 + (l & 15);
        int k = s * 32 + (l >> 4) * 8;
        uint4 v = *reinterpret_cast<const uint4*>(&Wtblk[(size_t)col * K + k]);
        *reinterpret_cast<uint4*>(&Bs[(size_t)i * 8]) = v;
    }
    __syncthreads();

    const unsigned short* Bl = Bs + (size_t)lane * 8;
    const int stride = gridDim.x;
    int g = blockIdx.x;
    if (g >= nstrip) return;

    uint4 uA[KS], uB[KS];

    auto loadA = [&](int gg, uint4* u) {
        int arow = gg * 128 + wave * 16 + l15;
        const unsigned short* Ar = A + (size_t)arow * K + l4 * 8;
        #pragma unroll
        for (int s = 0; s < KS; ++s)
            u[s] = *reinterpret_cast<const uint4*>(Ar + s * 32);
    };

    auto compute = [&](int gc, uint4* u) {
        f32x4 acc[NF] = {};
        #pragma unroll
        for (int s = 0; s < KS; ++s) {
            union { uint4 q; short8 v; } cv;
            cv.q = u[s];
            short8 af = cv.v;
            #pragma unroll
            for (int n = 0; n < NF; ++n) {
                short8 bf = *reinterpret_cast<const short8*>(Bl + (size_t)(s * NF + n) * 512);
                acc[n] = __builtin_amdgcn_mfma_f32_16x16x32_bf16(af, bf, acc[n], 0, 0, 0);
            }
        }
        const int rbase = gc * 128 + wave * 16;
        #pragma unroll
        for (int n = 0; n < NF; ++n) {
            #pragma unroll
            for (int r = 0; r < 4; ++r) {
                int rw = rbase + l4 * 4 + r;
                if constexpr (YSPLIT) {
                    int col = n * 16 + l15;
                    if (out8) N8[(size_t)rw * 128 + col] = enc8(acc[n][r]);
                    else      S16[(size_t)rw * 128 + col] = f2bf(acc[n][r]);
                } else {
                    if (n < 4) S16[(size_t)rw * 64 + n * 16 + l15] = f2bf(acc[n][r]);
                    else       N8[(size_t)rw * 64 + (n - 4) * 16 + l15] = enc8(acc[n][r]);
                }
            }
        }
    };

    loadA(g, uA);
    while (true) {
        int gn = g + stride;
        if (gn < nstrip) loadA(gn, uB);
        compute(g, uA);
        if (gn >= nstrip) break;
        g = gn;
        gn = g + stride;
        if (gn < nstrip) loadA(gn, uA);
        compute(g, uB);
        if (gn >= nstrip) break;
        g = gn;
    }
}

// ---------------- FUSED: layer-1 aggregate + relu -> h (LDS) -> layer-2 GEMM ----------------
// 256 thr = 4 waves; block owns 16 nodes (wave w: nodes w*4..w*4+3, gathered as in round-10 agg1).
// h rows staged in LDS [16][136] bf16 (padded, 2-way-free reads); Wt2 staged fragment-ordered
// (32KB, conflict-free). MFMA 16x16x32: KS=4, NF=8 frags split 2/wave. cols<64 -> t2s bf16,
// cols>=64 -> t2n fp8. Output buffers MUST NOT alias t1s/t1n (other blocks still gather them).
__global__ __launch_bounds__(256) void k_agg1f(const uint2* __restrict__ t1n, const uint4* __restrict__ t1s,
                                               const int* __restrict__ rs, const int* __restrict__ ss,
                                               const float* __restrict__ dinv, const float* __restrict__ b1,
                                               const unsigned short* __restrict__ Wt2,
                                               unsigned short* __restrict__ t2s,
                                               unsigned char* __restrict__ t2n, int N) {
    __shared__ unsigned short Bs[32 * 512];   // 32KB Wt2 fragment-ordered
    __shared__ unsigned short Hs[16 * 136];   // 16 h-rows, padded to 136 shorts
    const int tid = threadIdx.x;
    const int wave = tid >> 6, lane = tid & 63;
    const int l15 = lane & 15, l4 = lane >> 4;

    // stage Wt2: frag f = s*8+n occupies 1KB, lane l's 16B at f*1024 + l*16
    for (int i = tid; i < 32 * 64; i += 256) {
        int f = i >> 6, l = i & 63;
        int s = f >> 3, n = f & 7;
        int col = n * 16 + (l & 15);
        int k = s * 32 + (l >> 4) * 8;
        uint4 v = *reinterpret_cast<const uint4*>(&Wt2[(size_t)col * 128 + k]);
        *reinterpret_cast<uint4*>(&Bs[(size_t)i * 8]) = v;
    }

    const int nb = blockIdx.x * 16;
    const int q = lane >> 4, c = lane & 15;

    // gather phase: 4 nodes per wave
    for (int j = 0; j < 4; ++j) {
        int wid = nb + wave * 4 + j;
        int row = wave * 4 + j;
        if (wid < N) {
            int e0 = rs[wid], e1 = rs[wid + 1];
            f32x2 acc[4] = {};
            int e = e0;
            for (; e + 16 <= e1; e += 16) {
                int s0 = ss[e + q];
                int s1 = ss[e + 4 + q];
                int s2 = ss[e + 8 + q];
                int s3 = ss[e + 12 + q];
                uint2 v0 = t1n[(size_t)s0 * 16 + c];
                uint2 v1 = t1n[(size_t)s1 * 16 + c];
                uint2 v2 = t1n[(size_t)s2 * 16 + c];
                uint2 v3 = t1n[(size_t)s3 * 16 + c];
                acc8(acc, v0); acc8(acc, v1); acc8(acc, v2); acc8(acc, v3);
            }
            for (; e < e1; e += 4) {
                if (e + q < e1) {
                    uint2 v = t1n[(size_t)ss[e + q] * 16 + c];
                    acc8(acc, v);
                }
            }
            #pragma unroll
            for (int t = 0; t < 4; ++t) {
                acc[t] += shfl_xor2(acc[t], 16);
                acc[t] += shfl_xor2(acc[t], 32);
            }
            if (lane < 16) {
                float di = dinv[wid];
                uint4 sv = t1s[(size_t)wid * 16 + c];
                float4 bA = *reinterpret_cast<const float4*>(&b1[c * 8]);
                float4 bB = *reinterpret_cast<const float4*>(&b1[c * 8 + 4]);
                float h0 = fmaxf(fmaf(acc[0][0], di, bf_lo(sv.x)) + bA.x, 0.f);
                float h1 = fmaxf(fmaf(acc[0][1], di, bf_hi(sv.x)) + bA.y, 0.f);
                float h2 = fmaxf(fmaf(acc[1][0], di, bf_lo(sv.y)) + bA.z, 0.f);
                float h3 = fmaxf(fmaf(acc[1][1], di, bf_hi(sv.y)) + bA.w, 0.f);
                float h4 = fmaxf(fmaf(acc[2][0], di, bf_lo(sv.z)) + bB.x, 0.f);
                float h5 = fmaxf(fmaf(acc[2][1], di, bf_hi(sv.z)) + bB.y, 0.f);
                float h6 = fmaxf(fmaf(acc[3][0], di, bf_lo(sv.w)) + bB.z, 0.f);
                float h7 = fmaxf(fmaf(acc[3][1], di, bf_hi(sv.w)) + bB.w, 0.f);
                uint4 o;
                o.x = pack2bf(h0, h1); o.y = pack2bf(h2, h3);
                o.z = pack2bf(h4, h5); o.w = pack2bf(h6, h7);
                *reinterpret_cast<uint4*>(&Hs[row * 136 + lane * 8]) = o;
            }
        } else if (lane < 16) {
            uint4 z = make_uint4(0u, 0u, 0u, 0u);
            *reinterpret_cast<uint4*>(&Hs[row * 136 + lane * 8]) = z;
        }
    }
    __syncthreads();

    // MFMA phase: wave computes frags n = wave*2, wave*2+1 over 16 rows
    const unsigned short* Bl = Bs + (size_t)lane * 8;
    f32x4 acc2[2] = {};
    #pragma unroll
    for (int s = 0; s < 4; ++s) {
        union { uint4 qq; short8 v; } cv;
        cv.qq = *reinterpret_cast<const uint4*>(&Hs[l15 * 136 + s * 32 + l4 * 8]);
        short8 af = cv.v;
        #pragma unroll
        for (int t = 0; t < 2; ++t) {
            int n = wave * 2 + t;
            short8 bf = *reinterpret_cast<const short8*>(Bl + (size_t)(s * 8 + n) * 512);
            acc2[t] = __builtin_amdgcn_mfma_f32_16x16x32_bf16(af, bf, acc2[t], 0, 0, 0);
        }
    }
    #pragma unroll
    for (int t = 0; t < 2; ++t) {
        int n = wave * 2 + t;
        #pragma unroll
        for (int r = 0; r < 4; ++r) {
            int rw = nb + l4 * 4 + r;
            if (rw < N) {
                int col = n * 16 + l15;
                if (n < 4) t2s[(size_t)rw * 64 + col] = f2bf(acc2[t][r]);
                else       t2n[(size_t)rw * 64 + (col - 64)] = enc8(acc2[t][r]);
            }
        }
    }
}

// ---------------- layer-2 aggregate + combine -> out (f32) ----------------
// one wave/node; 8 lanes/row (uint2 = 8 fp8 cols); 32 edges/iter, 4 gathers in flight.
__global__ __launch_bounds__(256) void k_agg2(const uint2* __restrict__ t2n, const uint4* __restrict__ t2s,
                                              const int* __restrict__ rs, const int* __restrict__ ss,
                                              const float* __restrict__ dinv, const float* __restrict__ b2,
                                              float* __restrict__ out, int N) {
    int wid  = (blockIdx.x * blockDim.x + threadIdx.x) >> 6;
    int lane = threadIdx.x & 63;
    if (wid >= N) return;
    int e0 = rs[wid], e1 = rs[wid + 1];
    const int q = lane >> 3, c = lane & 7;
    f32x2 acc[4] = {};
    int e = e0;
    for (; e + 32 <= e1; e += 32) {
        int s0 = ss[e + q];
        int s1 = ss[e + 8 + q];
        int s2 = ss[e + 16 + q];
        int s3 = ss[e + 24 + q];
        uint2 v0 = t2n[(size_t)s0 * 8 + c];
        uint2 v1 = t2n[(size_t)s1 * 8 + c];
        uint2 v2 = t2n[(size_t)s2 * 8 + c];
        uint2 v3 = t2n[(size_t)s3 * 8 + c];
        acc8(acc, v0); acc8(acc, v1); acc8(acc, v2); acc8(acc, v3);
    }
    for (; e < e1; e += 8) {
        if (e + q < e1) {
            uint2 v = t2n[(size_t)ss[e + q] * 8 + c];
            acc8(acc, v);
        }
    }
    #pragma unroll
    for (int j = 0; j < 4; ++j) {
        acc[j] += shfl_xor2(acc[j], 8);
        acc[j] += shfl_xor2(acc[j], 16);
        acc[j] += shfl_xor2(acc[j], 32);
    }
    if (lane < 8) {
        float di = dinv[wid];
        uint4 sv = t2s[(size_t)wid * 8 + c];
        float4 bA = *reinterpret_cast<const float4*>(&b2[c * 8]);
        float4 bB = *reinterpret_cast<const float4*>(&b2[c * 8 + 4]);
        float4 oA, oB;
        oA.x = fmaf(acc[0][0], di, bf_lo(sv.x)) + bA.x;
        oA.y = fmaf(acc[0][1], di, bf_hi(sv.x)) + bA.y;
        oA.z = fmaf(acc[1][0], di, bf_lo(sv.y)) + bA.z;
        oA.w = fmaf(acc[1][1], di, bf_hi(sv.y)) + bA.w;
        oB.x = fmaf(acc[2][0], di, bf_lo(sv.z)) + bB.x;
        oB.y = fmaf(acc[2][1], di, bf_hi(sv.z)) + bB.y;
        oB.z = fmaf(acc[3][0], di, bf_lo(sv.w)) + bB.z;
        oB.w = fmaf(acc[3][1], di, bf_hi(sv.w)) + bB.w;
        *reinterpret_cast<float4*>(&out[(size_t)wid * 64 + c * 8]) = oA;
        *reinterpret_cast<float4*>(&out[(size_t)wid * 64 + c * 8 + 4]) = oB;
    }
}

extern "C" void kernel_launch(void* const* d_in, const int* in_sizes, int n_in,
                              void* d_out, int out_size, void* d_ws, size_t ws_size,
                              hipStream_t stream) {
    const float* x   = (const float*)d_in[0];
    const int*   src = (const int*)d_in[1];
    const int*   dst = (const int*)d_in[2];
    const float* W1s = (const float*)d_in[3];
    const float* W1n = (const float*)d_in[4];
    const float* b1  = (const float*)d_in[5];
    const float* W2s = (const float*)d_in[6];
    const float* W2n = (const float*)d_in[7];
    const float* b2  = (const float*)d_in[8];
    float* out = (float*)d_out;

    const int IN = 256, H = 128, OUT = 64;
    const int N  = in_sizes[0] / IN;
    const int E  = in_sizes[1];
    const int Mpad = (N + 127) & ~127;
    const int NBF = (N + 127) >> 7;       // fine buckets (128 nodes)
    const int NQ  = (N + 4095) >> 12;     // coarse buckets (4096 nodes)

    char* ws = (char*)d_ws;
    size_t off = 0;
    auto alloc = [&](size_t bytes) -> char* {
        char* p = ws + off;
        off = (off + bytes + 255) & ~(size_t)255;
        return p;
    };
    int*   row_start  = (int*)  alloc((size_t)(N + 1) * 4);
    float* deg_inv    = (float*)alloc((size_t)N * 4);
    int*   bcnt       = (int*)  alloc((size_t)NBMAX * 4);
    int*   boffs      = (int*)  alloc((size_t)(NBMAX + 1) * 4);
    int*   gfill_fine = (int*)  alloc((size_t)NBMAX * 4);
    int*   gfillq     = (int*)  alloc((size_t)NQMAX * 4);
    int*   src_sorted = (int*)  alloc((size_t)E * 4);
    uint32* pairs1    = (uint32*)alloc((size_t)E * 4);
    uint32* pairs2    = (uint32*)alloc((size_t)E * 4);
    unsigned short* xb  = (unsigned short*)alloc((size_t)Mpad * IN * 2);  // bf16 x (pad rows zero)
    unsigned short* Wt1 = (unsigned short*)alloc((size_t)(2 * H) * IN * 2);
    unsigned short* Wt2 = (unsigned short*)alloc((size_t)(2 * OUT) * H * 2);
    unsigned short* t1s = (unsigned short*)alloc((size_t)Mpad * H * 2);  // bf16 self (layer 1)
    unsigned char*  t1n = (unsigned char*) alloc((size_t)Mpad * H);     // fp8 neigh (layer 1)
    unsigned short* t2s = (unsigned short*)alloc((size_t)Mpad * OUT * 2); // bf16 self (layer 2)
    unsigned char*  t2n = (unsigned char*) alloc((size_t)Mpad * OUT);    // fp8 neigh (layer 2)

    // 1. CSR build: fine hist -> scan -> coarse scatter -> fine scatter -> bucket sort
    hipMemsetAsync(bcnt, 0, (size_t)NBMAX * 4, stream);
    int nblk = (E + EPB - 1) / EPB;
    k_hist_fine     <<<nblk, 256, 0, stream>>>(dst, E, bcnt);
    k_scan          <<<1, 1024, 0, stream>>>(bcnt, NBF, NQ, boffs, gfill_fine, gfillq, E);
    k_scatter_coarse<<<nblk, 256, 0, stream>>>(src, dst, E, gfillq, pairs1);
    k_scatter_fine  <<<dim3(NQ, 32), 256, 0, stream>>>(pairs1, boffs, gfillq, gfill_fine, pairs2, 32);
    k_bucket_sort   <<<NBF, 256, 0, stream>>>(pairs2, boffs, N, E, row_start, deg_inv, src_sorted);

    // 2. casts: x -> bf16 (pad rows zero), weights transpose+cast
    long n8 = (long)N * IN / 8, total8 = (long)Mpad * IN / 8;
    k_cast_x<<<(int)((total8 + 255) / 256), 256, 0, stream>>>(x, (uint32*)xb, n8, total8);
    k_wt<<<(2 * H * IN + 255) / 256, 256, 0, stream>>>(W1s, W1n, IN, 8, H, Wt1);
    k_wt<<<(2 * OUT * H + 255) / 256, 256, 0, stream>>>(W2s, W2n, H, 7, OUT, Wt2);

    // 3. layer 1 GEMM: xb -> t1s bf16 [Mpad x 128] (y=0), t1n fp8 [Mpad x 128] (y=1)
    int nstrip1 = Mpad / 128;
    gemm_rs<256, 8, true><<<dim3(256, 2), 512, 0, stream>>>(xb, nstrip1, Wt1, t1s, t1n);
    // 4. FUSED: aggregate + relu -> h (LDS) -> layer-2 GEMM -> t2s/t2n
    k_agg1f<<<(N + 15) / 16, 256, 0, stream>>>((const uint2*)t1n, (const uint4*)t1s,
                                               row_start, src_sorted, deg_inv, b1, Wt2,
                                               t2s, t2n, N);
    // 5. aggregate -> out f32
    k_agg2<<<(N + 3) / 4, 256, 0, stream>>>((const uint2*)t2n, (const uint4*)t2s,
                                            row_start, src_sorted, deg_inv, b2, out, N);
}

// Round 15
// 301.745 us; speedup vs baseline: 1.1795x; 1.1795x over previous
//
#include <hip/hip_runtime.h>
#include <hip/hip_bf16.h>

// GraphSAGE 2-layer: radix-bucket CSR build + bf16 MFMA transform-then-aggregate.
// N=100000, E=3.2M, IN=256, H=128, OUT=64.
// Round-13 structure + fat prologue kernel (cast_x | hist_fine | wt1 | wt2 merged)
// + balanced gemm L1 grid. Aggs: uint2 fp8 gathers, packed cvt/add, high occupancy.

typedef unsigned int uint32;
typedef __attribute__((ext_vector_type(8))) short short8;
typedef __attribute__((ext_vector_type(4))) float f32x4;
typedef __attribute__((ext_vector_type(2))) float f32x2;

#define NBMAX 1024     // max fine buckets (N <= 131072 at 128 nodes/bucket)
#define NQMAX 32       // max coarse buckets (4096 nodes each)
#define EPB   4096     // edges per block in hist/scatter passes

#if defined(__has_builtin)
#if __has_builtin(__builtin_amdgcn_cvt_pk_f32_fp8) && __has_builtin(__builtin_amdgcn_cvt_pk_fp8_f32)
#define FP8_HW 1
#endif
#endif
#ifndef FP8_HW
#define FP8_HW 0
#endif

__device__ __forceinline__ unsigned short f2bf(float f) {
    unsigned u = __float_as_uint(f);
    u += 0x7fffu + ((u >> 16) & 1u);      // RNE
    return (unsigned short)(u >> 16);
}
__device__ __forceinline__ uint32 pack2bf(float lo, float hi) {
    return (uint32)f2bf(lo) | ((uint32)f2bf(hi) << 16);
}
__device__ __forceinline__ float bf_lo(uint32 v) { return __uint_as_float(v << 16); }
__device__ __forceinline__ float bf_hi(uint32 v) { return __uint_as_float(v & 0xFFFF0000u); }

// ---- fp8 e4m3 encode/decode ----
__device__ __forceinline__ unsigned char enc8(float v) {
#if FP8_HW
    return (unsigned char)(__builtin_amdgcn_cvt_pk_fp8_f32(v, v, 0, false) & 0xFF);
#else
    float g = v * 0x1p-120f;
    uint32 b = __float_as_uint(g);
    uint32 s = (b >> 24) & 0x80u;
    b &= 0x7fffffffu;
    b += 0x7ffffu + ((b >> 20) & 1u);     // RNE to 3 mantissa bits
    int t = (int)(b >> 20) - 960;
    t = t < 0 ? 0 : (t > 126 ? 126 : t);
    return (unsigned char)(s | (uint32)t);
#endif
}
#if !FP8_HW
__device__ __forceinline__ float dec1(uint32 b) {
    uint32 bits = ((b & 0x80u) << 24) | ((b & 0x7fu) << 20);
    return __uint_as_float(bits) * 0x1p+120f;
}
#endif

// decode 2 fp8 (word lo/hi of u, compile-time selector) -> packed float pair
template<bool HI>
__device__ __forceinline__ f32x2 cvt2(uint32 u) {
#if FP8_HW
    auto t = __builtin_amdgcn_cvt_pk_f32_fp8(u, HI);
    f32x2 r; r[0] = t[0]; r[1] = t[1];
    return r;
#else
    uint32 a = HI ? (u >> 16) : u;
    f32x2 r; r[0] = dec1(a & 0xffu); r[1] = dec1((a >> 8) & 0xffu);
    return r;
#endif
}

// accumulate 8 fp8 values (uint2) into 4 packed-pair accumulators
__device__ __forceinline__ void acc8(f32x2* acc, uint2 v) {
    acc[0] += cvt2<false>(v.x); acc[1] += cvt2<true>(v.x);
    acc[2] += cvt2<false>(v.y); acc[3] += cvt2<true>(v.y);
}

__device__ __forceinline__ f32x2 shfl_xor2(f32x2 v, int m) {
    union { f32x2 f; long long l; } u;
    u.f = v;
    u.l = __shfl_xor(u.l, m);
    return u.f;
}

// ---------------- fat prologue: cast_x | hist_fine | wt1 | wt2 (independent works) ----------------
__global__ __launch_bounds__(256) void k_prep(const float* __restrict__ x, uint32* __restrict__ xb,
                                              long n8, long total8, int nblk_cast,
                                              const int* __restrict__ dst, int E, int* __restrict__ bcnt,
                                              int nblk_hist,
                                              const float* __restrict__ W1s, const float* __restrict__ W1n,
                                              unsigned short* __restrict__ Wt1, int nblk_w1,
                                              const float* __restrict__ W2s, const float* __restrict__ W2n,
                                              unsigned short* __restrict__ Wt2) {
    __shared__ int hist[NBMAX];
    int b = blockIdx.x;
    if (b < nblk_cast) {
        long t = (long)b * 256 + threadIdx.x;
        if (t < total8) {
            uint4 o = make_uint4(0u, 0u, 0u, 0u);
            if (t < n8) {
                const float4* p = reinterpret_cast<const float4*>(x) + t * 2;
                float4 a = p[0], bb = p[1];
                o.x = pack2bf(a.x, a.y);  o.y = pack2bf(a.z, a.w);
                o.z = pack2bf(bb.x, bb.y); o.w = pack2bf(bb.z, bb.w);
            }
            reinterpret_cast<uint4*>(xb)[t] = o;
        }
        return;
    }
    b -= nblk_cast;
    if (b < nblk_hist) {
        for (int i = threadIdx.x; i < NBMAX; i += 256) hist[i] = 0;
        __syncthreads();
        int base = b * EPB;
        #pragma unroll 4
        for (int i = 0; i < EPB / 256; ++i) {
            int e = base + i * 256 + threadIdx.x;
            if (e < E) atomicAdd(&hist[dst[e] >> 7], 1);
        }
        __syncthreads();
        for (int i = threadIdx.x; i < NBMAX; i += 256) {
            int h = hist[i];
            if (h) atomicAdd(&bcnt[i], h);
        }
        return;
    }
    b -= nblk_hist;
    if (b < nblk_w1) {
        int t = b * 256 + threadIdx.x;
        if (t < 256 * 256) {       // 2*H x IN
            int c = t >> 8, k = t & 255;
            float v = (c < 128) ? W1s[(size_t)k * 128 + c] : W1n[(size_t)k * 128 + (c - 128)];
            Wt1[t] = f2bf(v);
        }
        return;
    }
    b -= nblk_w1;
    {
        int t = b * 256 + threadIdx.x;
        if (t < 128 * 128) {       // 2*OUT x H
            int c = t >> 7, k = t & 127;
            float v = (c < 64) ? W2s[(size_t)k * 64 + c] : W2n[(size_t)k * 64 + (c - 64)];
            Wt2[t] = f2bf(v);
        }
    }
}

// ---------------- scan: fine offsets + fills, coarse fills ----------------
__global__ __launch_bounds__(1024) void k_scan(const int* __restrict__ bcnt, int NBF, int NQ,
                                               int* __restrict__ boffs, int* __restrict__ gfill_fine,
                                               int* __restrict__ gfillq, int E) {
    __shared__ int sd[1024];
    int tid = threadIdx.x;
    int v = (tid < NBF) ? bcnt[tid] : 0;
    sd[tid] = v;
    __syncthreads();
    for (int off = 1; off < 1024; off <<= 1) {
        int t = (tid >= off) ? sd[tid - off] : 0;
        __syncthreads();
        sd[tid] += t;
        __syncthreads();
    }
    int excl = sd[tid] - v;
    if (tid < NBF) { boffs[tid] = excl; gfill_fine[tid] = excl; }
    if (tid == 0) boffs[NBF] = E;
    __syncthreads();
    if (tid < NQ) {
        int f = tid * 32;
        gfillq[tid] = (f < NBF) ? (sd[f] - ((f < NBF) ? bcnt[f] : 0)) : E;
    }
}

// ---------------- pass B: coarse scatter (q = dst >> 12) ----------------
__global__ __launch_bounds__(256) void k_scatter_coarse(const int* __restrict__ src,
                                                        const int* __restrict__ dst, int E,
                                                        int* __restrict__ gfillq,
                                                        uint32* __restrict__ pairs1) {
    __shared__ int hist[NQMAX];
    __shared__ int basea[NQMAX];
    if (threadIdx.x < NQMAX) hist[threadIdx.x] = 0;
    __syncthreads();
    int base = blockIdx.x * EPB;
    #pragma unroll 4
    for (int i = 0; i < EPB / 256; ++i) {
        int e = base + i * 256 + threadIdx.x;
        if (e < E) atomicAdd(&hist[dst[e] >> 12], 1);
    }
    __syncthreads();
    if (threadIdx.x < NQMAX) {
        int h = hist[threadIdx.x];
        basea[threadIdx.x] = h ? atomicAdd(&gfillq[threadIdx.x], h) : 0;
        hist[threadIdx.x] = 0;
    }
    __syncthreads();
    #pragma unroll 4
    for (int i = 0; i < EPB / 256; ++i) {
        int e = base + i * 256 + threadIdx.x;
        if (e < E) {
            int d = dst[e];
            int q = d >> 12;
            int pos = basea[q] + atomicAdd(&hist[q], 1);
            pairs1[pos] = ((uint32)src[e] << 12) | (uint32)(d & 4095);
        }
    }
}

// ---------------- pass C: fine scatter within coarse segments ----------------
__global__ __launch_bounds__(256) void k_scatter_fine(const uint32* __restrict__ pairs1,
                                                      const int* __restrict__ boffs,
                                                      const int* __restrict__ qend,
                                                      int* __restrict__ gfill_fine,
                                                      uint32* __restrict__ pairs2, int NC) {
    __shared__ int hist[32];
    __shared__ int basea[32];
    const int q = blockIdx.x;
    const int s0 = boffs[q * 32];
    const int s1 = qend[q];
    for (long cb = (long)s0 + (long)blockIdx.y * EPB; cb < s1; cb += (long)NC * EPB) {
        int cend = (int)((cb + EPB < s1) ? cb + EPB : s1);
        if (threadIdx.x < 32) hist[threadIdx.x] = 0;
        __syncthreads();
        for (int e = (int)cb + threadIdx.x; e < cend; e += 256)
            atomicAdd(&hist[(pairs1[e] >> 7) & 31], 1);
        __syncthreads();
        if (threadIdx.x < 32) {
            int h = hist[threadIdx.x];
            basea[threadIdx.x] = h ? atomicAdd(&gfill_fine[q * 32 + threadIdx.x], h) : 0;
            hist[threadIdx.x] = 0;
        }
        __syncthreads();
        for (int e = (int)cb + threadIdx.x; e < cend; e += 256) {
            uint32 p = pairs1[e];
            int fl = (p >> 7) & 31;
            int pos = basea[fl] + atomicAdd(&hist[fl], 1);
            pairs2[pos] = p;
        }
        __syncthreads();
    }
}

// ---------------- pass D: per-fine-bucket sort -> CSR ----------------
__global__ __launch_bounds__(256) void k_bucket_sort(const uint32* __restrict__ pairs,
                                                     const int* __restrict__ boffs,
                                                     int N, int E,
                                                     int* __restrict__ row_start,
                                                     float* __restrict__ deg_inv,
                                                     int* __restrict__ src_sorted) {
    __shared__ int cnt[128];
    __shared__ int sc[128];
    __shared__ int fill[128];
    int b = blockIdx.x, tid = threadIdx.x;
    int s0 = boffs[b], s1 = boffs[b + 1];
    if (tid < 128) cnt[tid] = 0;
    __syncthreads();
    for (int e = s0 + tid; e < s1; e += 256)
        atomicAdd(&cnt[pairs[e] & 127], 1);
    __syncthreads();
    if (tid < 128) sc[tid] = cnt[tid];
    __syncthreads();
    for (int off = 1; off < 128; off <<= 1) {
        int v = 0;
        if (tid < 128 && tid >= off) v = sc[tid - off];
        __syncthreads();
        if (tid < 128) sc[tid] += v;
        __syncthreads();
    }
    if (tid < 128) {
        int excl = sc[tid] - cnt[tid];
        int node = b * 128 + tid;
        if (node < N) {
            row_start[node] = s0 + excl;
            int d = cnt[tid];
            deg_inv[node] = 1.0f / (float)(d > 1 ? d : 1);
        }
        fill[tid] = s0 + excl;
    }
    if (b == 0 && tid == 0) row_start[N] = E;
    __syncthreads();
    for (int e = s0 + tid; e < s1; e += 256) {
        uint32 p = pairs[e];
        int pos = atomicAdd(&fill[p & 127], 1);
        src_sorted[pos] = (int)(p >> 12);
    }
}

// ---------------- register-streaming MFMA GEMM, fragment-ordered B in LDS ----------------
template<int K, int NF, bool YSPLIT>
__global__ __launch_bounds__(512) void gemm_rs(const unsigned short* __restrict__ A, int nstrip,
                                               const unsigned short* __restrict__ Wt,
                                               unsigned short* __restrict__ S16,
                                               unsigned char* __restrict__ N8) {
    constexpr int KS = K / 32;
    __shared__ unsigned short Bs[NF * KS * 512];
    const int tid = threadIdx.x;
    const int wave = tid >> 6, lane = tid & 63;
    const int l15 = lane & 15, l4 = lane >> 4;

    const unsigned short* Wtblk = Wt + (YSPLIT ? (size_t)blockIdx.y * 128 * K : 0);
    const bool out8 = YSPLIT && (blockIdx.y == 1);

    for (int i = tid; i < NF * KS * 64; i += 512) {
        int f = i >> 6, l = i & 63;
        int s = f / NF, n = f - s * NF;
        int col = n * 16 + (l & 15);
        int k = s * 32 + (l >> 4) * 8;
        uint4 v = *reinterpret_cast<const uint4*>(&Wtblk[(size_t)col * K + k]);
        *reinterpret_cast<uint4*>(&Bs[(size_t)i * 8]) = v;
    }
    __syncthreads();

    const unsigned short* Bl = Bs + (size_t)lane * 8;
    const int stride = gridDim.x;
    int g = blockIdx.x;
    if (g >= nstrip) return;

    uint4 uA[KS], uB[KS];

    auto loadA = [&](int gg, uint4* u) {
        int arow = gg * 128 + wave * 16 + l15;
        const unsigned short* Ar = A + (size_t)arow * K + l4 * 8;
        #pragma unroll
        for (int s = 0; s < KS; ++s)
            u[s] = *reinterpret_cast<const uint4*>(Ar + s * 32);
    };

    auto compute = [&](int gc, uint4* u) {
        f32x4 acc[NF] = {};
        #pragma unroll
        for (int s = 0; s < KS; ++s) {
            union { uint4 q; short8 v; } cv;
            cv.q = u[s];
            short8 af = cv.v;
            #pragma unroll
            for (int n = 0; n < NF; ++n) {
                short8 bf = *reinterpret_cast<const short8*>(Bl + (size_t)(s * NF + n) * 512);
                acc[n] = __builtin_amdgcn_mfma_f32_16x16x32_bf16(af, bf, acc[n], 0, 0, 0);
            }
        }
        const int rbase = gc * 128 + wave * 16;
        #pragma unroll
        for (int n = 0; n < NF; ++n) {
            #pragma unroll
            for (int r = 0; r < 4; ++r) {
                int rw = rbase + l4 * 4 + r;
                if constexpr (YSPLIT) {
                    int col = n * 16 + l15;
                    if (out8) N8[(size_t)rw * 128 + col] = enc8(acc[n][r]);
                    else      S16[(size_t)rw * 128 + col] = f2bf(acc[n][r]);
                } else {
                    if (n < 4) S16[(size_t)rw * 64 + n * 16 + l15] = f2bf(acc[n][r]);
                    else       N8[(size_t)rw * 64 + (n - 4) * 16 + l15] = enc8(acc[n][r]);
                }
            }
        }
    };

    loadA(g, uA);
    while (true) {
        int gn = g + stride;
        if (gn < nstrip) loadA(gn, uB);
        compute(g, uA);
        if (gn >= nstrip) break;
        g = gn;
        gn = g + stride;
        if (gn < nstrip) loadA(gn, uA);
        compute(g, uB);
        if (gn >= nstrip) break;
        g = gn;
    }
}

// ---------------- layer-1 aggregate + combine + relu -> h (bf16) ----------------
// one wave/node; 16 lanes/row (uint2 = 8 fp8 cols); 16 edges/iter, 4 gathers in flight;
// packed decode (cvt_pk_f32_fp8) + f32x2 accumulation.
__global__ __launch_bounds__(256) void k_agg1(const uint2* __restrict__ t1n, const uint4* __restrict__ t1s,
                                              const int* __restrict__ rs, const int* __restrict__ ss,
                                              const float* __restrict__ dinv, const float* __restrict__ b1,
                                              uint4* __restrict__ h, int N) {
    int wid  = (blockIdx.x * blockDim.x + threadIdx.x) >> 6;
    int lane = threadIdx.x & 63;
    if (wid >= N) return;
    int e0 = rs[wid], e1 = rs[wid + 1];
    const int q = lane >> 4, c = lane & 15;
    f32x2 acc[4] = {};
    int e = e0;
    for (; e + 16 <= e1; e += 16) {
        int s0 = ss[e + q];
        int s1 = ss[e + 4 + q];
        int s2 = ss[e + 8 + q];
        int s3 = ss[e + 12 + q];
        uint2 v0 = t1n[(size_t)s0 * 16 + c];
        uint2 v1 = t1n[(size_t)s1 * 16 + c];
        uint2 v2 = t1n[(size_t)s2 * 16 + c];
        uint2 v3 = t1n[(size_t)s3 * 16 + c];
        acc8(acc, v0); acc8(acc, v1); acc8(acc, v2); acc8(acc, v3);
    }
    for (; e < e1; e += 4) {
        if (e + q < e1) {
            uint2 v = t1n[(size_t)ss[e + q] * 16 + c];
            acc8(acc, v);
        }
    }
    #pragma unroll
    for (int j = 0; j < 4; ++j) {
        acc[j] += shfl_xor2(acc[j], 16);
        acc[j] += shfl_xor2(acc[j], 32);
    }
    if (lane < 16) {
        float di = dinv[wid];
        uint4 sv = t1s[(size_t)wid * 16 + c];
        float4 bA = *reinterpret_cast<const float4*>(&b1[c * 8]);
        float4 bB = *reinterpret_cast<const float4*>(&b1[c * 8 + 4]);
        float h0 = fmaxf(fmaf(acc[0][0], di, bf_lo(sv.x)) + bA.x, 0.f);
        float h1 = fmaxf(fmaf(acc[0][1], di, bf_hi(sv.x)) + bA.y, 0.f);
        float h2 = fmaxf(fmaf(acc[1][0], di, bf_lo(sv.y)) + bA.z, 0.f);
        float h3 = fmaxf(fmaf(acc[1][1], di, bf_hi(sv.y)) + bA.w, 0.f);
        float h4 = fmaxf(fmaf(acc[2][0], di, bf_lo(sv.z)) + bB.x, 0.f);
        float h5 = fmaxf(fmaf(acc[2][1], di, bf_hi(sv.z)) + bB.y, 0.f);
        float h6 = fmaxf(fmaf(acc[3][0], di, bf_lo(sv.w)) + bB.z, 0.f);
        float h7 = fmaxf(fmaf(acc[3][1], di, bf_hi(sv.w)) + bB.w, 0.f);
        uint4 o;
        o.x = pack2bf(h0, h1); o.y = pack2bf(h2, h3);
        o.z = pack2bf(h4, h5); o.w = pack2bf(h6, h7);
        h[(size_t)wid * 16 + c] = o;
    }
}

// ---------------- layer-2 aggregate + combine -> out (f32) ----------------
// one wave/node; 8 lanes/row (uint2 = 8 fp8 cols); 32 edges/iter, 4 gathers in flight;
// packed decode + f32x2 accumulation.
__global__ __launch_bounds__(256) void k_agg2(const uint2* __restrict__ t2n, const uint4* __restrict__ t2s,
                                              const int* __restrict__ rs, const int* __restrict__ ss,
                                              const float* __restrict__ dinv, const float* __restrict__ b2,
                                              float* __restrict__ out, int N) {
    int wid  = (blockIdx.x * blockDim.x + threadIdx.x) >> 6;
    int lane = threadIdx.x & 63;
    if (wid >= N) return;
    int e0 = rs[wid], e1 = rs[wid + 1];
    const int q = lane >> 3, c = lane & 7;
    f32x2 acc[4] = {};
    int e = e0;
    for (; e + 32 <= e1; e += 32) {
        int s0 = ss[e + q];
        int s1 = ss[e + 8 + q];
        int s2 = ss[e + 16 + q];
        int s3 = ss[e + 24 + q];
        uint2 v0 = t2n[(size_t)s0 * 8 + c];
        uint2 v1 = t2n[(size_t)s1 * 8 + c];
        uint2 v2 = t2n[(size_t)s2 * 8 + c];
        uint2 v3 = t2n[(size_t)s3 * 8 + c];
        acc8(acc, v0); acc8(acc, v1); acc8(acc, v2); acc8(acc, v3);
    }
    for (; e < e1; e += 8) {
        if (e + q < e1) {
            uint2 v = t2n[(size_t)ss[e + q] * 8 + c];
            acc8(acc, v);
        }
    }
    #pragma unroll
    for (int j = 0; j < 4; ++j) {
        acc[j] += shfl_xor2(acc[j], 8);
        acc[j] += shfl_xor2(acc[j], 16);
        acc[j] += shfl_xor2(acc[j], 32);
    }
    if (lane < 8) {
        float di = dinv[wid];
        uint4 sv = t2s[(size_t)wid * 8 + c];
        float4 bA = *reinterpret_cast<const float4*>(&b2[c * 8]);
        float4 bB = *reinterpret_cast<const float4*>(&b2[c * 8 + 4]);
        float4 oA, oB;
        oA.x = fmaf(acc[0][0], di, bf_lo(sv.x)) + bA.x;
        oA.y = fmaf(acc[0][1], di, bf_hi(sv.x)) + bA.y;
        oA.z = fmaf(acc[1][0], di, bf_lo(sv.y)) + bA.z;
        oA.w = fmaf(acc[1][1], di, bf_hi(sv.y)) + bA.w;
        oB.x = fmaf(acc[2][0], di, bf_lo(sv.z)) + bB.x;
        oB.y = fmaf(acc[2][1], di, bf_hi(sv.z)) + bB.y;
        oB.z = fmaf(acc[3][0], di, bf_lo(sv.w)) + bB.z;
        oB.w = fmaf(acc[3][1], di, bf_hi(sv.w)) + bB.w;
        *reinterpret_cast<float4*>(&out[(size_t)wid * 64 + c * 8]) = oA;
        *reinterpret_cast<float4*>(&out[(size_t)wid * 64 + c * 8 + 4]) = oB;
    }
}

extern "C" void kernel_launch(void* const* d_in, const int* in_sizes, int n_in,
                              void* d_out, int out_size, void* d_ws, size_t ws_size,
                              hipStream_t stream) {
    const float* x   = (const float*)d_in[0];
    const int*   src = (const int*)d_in[1];
    const int*   dst = (const int*)d_in[2];
    const float* W1s = (const float*)d_in[3];
    const float* W1n = (const float*)d_in[4];
    const float* b1  = (const float*)d_in[5];
    const float* W2s = (const float*)d_in[6];
    const float* W2n = (const float*)d_in[7];
    const float* b2  = (const float*)d_in[8];
    float* out = (float*)d_out;

    const int IN = 256, H = 128, OUT = 64;
    const int N  = in_sizes[0] / IN;
    const int E  = in_sizes[1];
    const int Mpad = (N + 127) & ~127;
    const int NBF = (N + 127) >> 7;       // fine buckets (128 nodes)
    const int NQ  = (N + 4095) >> 12;     // coarse buckets (4096 nodes)

    char* ws = (char*)d_ws;
    size_t off = 0;
    auto alloc = [&](size_t bytes) -> char* {
        char* p = ws + off;
        off = (off + bytes + 255) & ~(size_t)255;
        return p;
    };
    int*   row_start  = (int*)  alloc((size_t)(N + 1) * 4);
    float* deg_inv    = (float*)alloc((size_t)N * 4);
    int*   bcnt       = (int*)  alloc((size_t)NBMAX * 4);
    int*   boffs      = (int*)  alloc((size_t)(NBMAX + 1) * 4);
    int*   gfill_fine = (int*)  alloc((size_t)NBMAX * 4);
    int*   gfillq     = (int*)  alloc((size_t)NQMAX * 4);
    int*   src_sorted = (int*)  alloc((size_t)E * 4);
    uint32* pairs1    = (uint32*)alloc((size_t)E * 4);
    uint32* pairs2    = (uint32*)alloc((size_t)E * 4);
    unsigned short* xb  = (unsigned short*)alloc((size_t)Mpad * IN * 2);  // bf16 x (pad rows zero)
    unsigned short* Wt1 = (unsigned short*)alloc((size_t)(2 * H) * IN * 2);
    unsigned short* Wt2 = (unsigned short*)alloc((size_t)(2 * OUT) * H * 2);
    unsigned short* t1s = (unsigned short*)alloc((size_t)Mpad * H * 2);  // bf16 self; reused as t2s (ld 64)
    unsigned char*  t1n = (unsigned char*) alloc((size_t)Mpad * H);     // fp8 neigh; reused as t2n (ld 64)
    unsigned short* hbf = (unsigned short*)alloc((size_t)Mpad * H * 2); // layer-1 output (bf16)

    // 1. fat prologue: cast_x | fine hist | wt1 | wt2 (all independent)
    hipMemsetAsync(bcnt, 0, (size_t)NBMAX * 4, stream);
    long n8 = (long)N * IN / 8, total8 = (long)Mpad * IN / 8;
    int nblk_cast = (int)((total8 + 255) / 256);
    int nblk_hist = (E + EPB - 1) / EPB;
    int nblk_w1   = (2 * H * IN + 255) / 256;
    int nblk_w2   = (2 * OUT * H + 255) / 256;
    k_prep<<<nblk_cast + nblk_hist + nblk_w1 + nblk_w2, 256, 0, stream>>>(
        x, (uint32*)xb, n8, total8, nblk_cast,
        dst, E, bcnt, nblk_hist,
        W1s, W1n, Wt1, nblk_w1,
        W2s, W2n, Wt2);

    // 2. CSR: scan -> coarse scatter -> fine scatter -> bucket sort
    k_scan          <<<1, 1024, 0, stream>>>(bcnt, NBF, NQ, boffs, gfill_fine, gfillq, E);
    k_scatter_coarse<<<nblk_hist, 256, 0, stream>>>(src, dst, E, gfillq, pairs1);
    k_scatter_fine  <<<dim3(NQ, 32), 256, 0, stream>>>(pairs1, boffs, gfillq, gfill_fine, pairs2, 32);
    k_bucket_sort   <<<NBF, 256, 0, stream>>>(pairs2, boffs, N, E, row_start, deg_inv, src_sorted);

    // 3. layer 1 GEMM: xb -> t1s bf16 [Mpad x 128] (y=0), t1n fp8 [Mpad x 128] (y=1)
    int nstrip1 = Mpad / 128;
    int gx1 = (nstrip1 + 1) / 2;          // 2 strips per block, balanced
    gemm_rs<256, 8, true><<<dim3(gx1, 2), 512, 0, stream>>>(xb, nstrip1, Wt1, t1s, t1n);
    // 4. aggregate + relu -> h bf16
    k_agg1<<<(N + 3) / 4, 256, 0, stream>>>((const uint2*)t1n, (const uint4*)t1s,
                                            row_start, src_sorted, deg_inv, b1, (uint4*)hbf, N);
    // 5. layer 2 GEMM: hbf -> t2s bf16 [Mpad x 64] + t2n fp8 [Mpad x 64] (reuse t1s/t1n)
    int nstrip2 = Mpad / 128;
    int gx2 = (nstrip2 + 1) / 2;
    gemm_rs<128, 8, false><<<dim3(gx2, 1), 512, 0, stream>>>(hbf, nstrip2, Wt2, t1s, t1n);
    // 6. aggregate -> out f32
    k_agg2<<<(N + 3) / 4, 256, 0, stream>>>((const uint2*)t1n, (const uint4*)t1s,
                                            row_start, src_sorted, deg_inv, b2, out, N);
}